// Round 1
// baseline (768.370 us; speedup 1.0000x reference)
//
#include <hip/hip_runtime.h>

#define N_NODES 100000
#define N_EDGES 1600000
#define IN_DIM  256
#define OUT_DIM 64
#define NEG_SLOPE 0.01f

// ---------- order-preserving float<->uint encoding for atomicMax ----------
__device__ __forceinline__ unsigned enc_f(float f) {
    unsigned u = __float_as_uint(f);
    return (u & 0x80000000u) ? ~u : (u | 0x80000000u);
}
__device__ __forceinline__ float dec_f(unsigned u) {
    return (u & 0x80000000u) ? __uint_as_float(u & 0x7fffffffu)
                             : __uint_as_float(~u);
}

// ---------------- K1: z = h @ W^T, s_src = z.a_l, s_dst = z.a_r ----------------
// tile: 128 rows x 64 cols, K-chunks of 64. 256 threads, each 4 rows x 8 cols.
#define BM 128
#define BK 64
#define LDH 68   // padded LDS stride (float4-aligned, conflict-free)

__global__ __launch_bounds__(256) void k1_gemm(
        const float* __restrict__ h, const float* __restrict__ W,
        const float* __restrict__ a_attn, float* __restrict__ z,
        float* __restrict__ s_src, float* __restrict__ s_dst) {
    __shared__ float h_lds[BM * LDH];
    __shared__ float w_lds[OUT_DIM * LDH];
    const int t  = threadIdx.x;
    const int tx = t & 7;    // col group (0..7)
    const int ty = t >> 3;   // row group (0..31)
    const int rb = blockIdx.x * BM;

    float acc[4][8];
#pragma unroll
    for (int i = 0; i < 4; ++i)
#pragma unroll
        for (int j = 0; j < 8; ++j) acc[i][j] = 0.f;

    for (int kc = 0; kc < IN_DIM; kc += BK) {
        __syncthreads();
        // stage h tile: 128 x 64 floats = 2048 float4 -> 8 per thread
#pragma unroll
        for (int l = 0; l < 8; ++l) {
            int f = t + 256 * l;
            int r = f >> 4;
            int k4 = f & 15;
            float4 v = make_float4(0.f, 0.f, 0.f, 0.f);
            if (rb + r < N_NODES)
                v = *(const float4*)(h + (size_t)(rb + r) * IN_DIM + kc + k4 * 4);
            *(float4*)(&h_lds[r * LDH + k4 * 4]) = v;
        }
        // stage W tile: 64 x 64 floats = 1024 float4 -> 4 per thread
#pragma unroll
        for (int l = 0; l < 4; ++l) {
            int f = t + 256 * l;
            int r = f >> 4;
            int k4 = f & 15;
            float4 v = *(const float4*)(W + (size_t)r * IN_DIM + kc + k4 * 4);
            *(float4*)(&w_lds[r * LDH + k4 * 4]) = v;
        }
        __syncthreads();
#pragma unroll 4
        for (int k = 0; k < BK; k += 4) {
            float4 hv[4], wv[8];
#pragma unroll
            for (int i = 0; i < 4; ++i)
                hv[i] = *(const float4*)(&h_lds[(ty + 32 * i) * LDH + k]);
#pragma unroll
            for (int j = 0; j < 8; ++j)
                wv[j] = *(const float4*)(&w_lds[(tx + 8 * j) * LDH + k]);
#pragma unroll
            for (int i = 0; i < 4; ++i)
#pragma unroll
                for (int j = 0; j < 8; ++j) {
                    acc[i][j] = fmaf(hv[i].x, wv[j].x, acc[i][j]);
                    acc[i][j] = fmaf(hv[i].y, wv[j].y, acc[i][j]);
                    acc[i][j] = fmaf(hv[i].z, wv[j].z, acc[i][j]);
                    acc[i][j] = fmaf(hv[i].w, wv[j].w, acc[i][j]);
                }
        }
    }

    float al[8], ar[8];
#pragma unroll
    for (int j = 0; j < 8; ++j) {
        al[j] = a_attn[tx + 8 * j];
        ar[j] = a_attn[OUT_DIM + tx + 8 * j];
    }

#pragma unroll
    for (int i = 0; i < 4; ++i) {
        int row = rb + ty + 32 * i;
        bool ok = row < N_NODES;
        float ps = 0.f, pd = 0.f;
#pragma unroll
        for (int j = 0; j < 8; ++j) {
            if (ok) z[(size_t)row * OUT_DIM + tx + 8 * j] = acc[i][j];
            ps = fmaf(acc[i][j], al[j], ps);
            pd = fmaf(acc[i][j], ar[j], pd);
        }
        // reduce over the 8 lanes of the tx group (consecutive lanes)
#pragma unroll
        for (int m = 1; m < 8; m <<= 1) {
            ps += __shfl_xor(ps, m, 64);
            pd += __shfl_xor(pd, m, 64);
        }
        if (ok && tx == 0) { s_src[row] = ps; s_dst[row] = pd; }
    }
}

// ---------------- K2: e = leakyrelu(s_src[src]+s_dst[dst]); segment max ----------------
__global__ __launch_bounds__(256) void k2_edge(
        const int* __restrict__ src, const int* __restrict__ dst,
        const float* __restrict__ s_src, const float* __restrict__ s_dst,
        float* __restrict__ e_buf, unsigned* __restrict__ emax) {
    int i = blockIdx.x * 256 + threadIdx.x;
    if (i >= N_EDGES) return;
    int s = src[i], d = dst[i];
    float e = s_src[s] + s_dst[d];
    e = (e > 0.f) ? e : e * NEG_SLOPE;
    e_buf[i] = e;
    atomicMax(&emax[d], enc_f(e));
}

// ---------------- K3: ex = exp(e-emax); denom += ex; out[dst] += ex*z[src] ----------------
__global__ __launch_bounds__(256) void k3_scatter(
        const int* __restrict__ src, const int* __restrict__ dst,
        const float* __restrict__ e_buf, const unsigned* __restrict__ emax,
        const float* __restrict__ z, float* __restrict__ denom,
        float* __restrict__ out) {
    int lane = threadIdx.x & 63;
    int eidx = blockIdx.x * 4 + (threadIdx.x >> 6);
    if (eidx >= N_EDGES) return;
    int s = src[eidx], d = dst[eidx];
    float ex = __expf(e_buf[eidx] - dec_f(emax[d]));
    if (lane == 0) atomicAdd(&denom[d], ex);
    atomicAdd(&out[(size_t)d * OUT_DIM + lane], ex * z[(size_t)s * OUT_DIM + lane]);
}

// ---------------- K4: out /= denom ----------------
__global__ __launch_bounds__(256) void k4_norm(
        float* __restrict__ out, const float* __restrict__ denom) {
    int i = blockIdx.x * 256 + threadIdx.x;
    if (i >= N_NODES * OUT_DIM) return;
    float d = denom[i >> 6];
    out[i] *= (d > 0.f) ? (1.f / d) : 0.f;
}

extern "C" void kernel_launch(void* const* d_in, const int* in_sizes, int n_in,
                              void* d_out, int out_size, void* d_ws, size_t ws_size,
                              hipStream_t stream) {
    const float* h      = (const float*)d_in[0];
    const float* W      = (const float*)d_in[1];
    const float* a_attn = (const float*)d_in[2];
    const int*   ei     = (const int*)d_in[3];   // int32 per harness conversion
    const int* src = ei;
    const int* dst = ei + N_EDGES;
    float* out = (float*)d_out;

    // workspace layout
    char* ws = (char*)d_ws;
    float* z      = (float*)ws;                    ws += (size_t)N_NODES * OUT_DIM * 4;
    float* e_buf  = (float*)ws;                    ws += (size_t)N_EDGES * 4;
    float* s_src  = (float*)ws;                    ws += (size_t)N_NODES * 4;
    float* s_dst  = (float*)ws;                    ws += (size_t)N_NODES * 4;
    float* denom  = (float*)ws;                    ws += (size_t)N_NODES * 4;
    unsigned* emax = (unsigned*)ws;                ws += (size_t)N_NODES * 4;

    hipMemsetAsync(out,   0, (size_t)N_NODES * OUT_DIM * 4, stream);
    hipMemsetAsync(denom, 0, (size_t)N_NODES * 4, stream);
    hipMemsetAsync(emax,  0, (size_t)N_NODES * 4, stream);  // 0 < enc(-inf): below all real values

    k1_gemm<<<(N_NODES + BM - 1) / BM, 256, 0, stream>>>(h, W, a_attn, z, s_src, s_dst);
    k2_edge<<<(N_EDGES + 255) / 256, 256, 0, stream>>>(src, dst, s_src, s_dst, e_buf, emax);
    k3_scatter<<<(N_EDGES + 3) / 4, 256, 0, stream>>>(src, dst, e_buf, emax, z, denom, out);
    k4_norm<<<(N_NODES * OUT_DIM + 255) / 256, 256, 0, stream>>>(out, denom);
}

// Round 2
// 488.890 us; speedup vs baseline: 1.5717x; 1.5717x over previous
//
#include <hip/hip_runtime.h>

#define N_NODES 100000
#define N_EDGES 1600000
#define IN_DIM  256
#define OUT_DIM 64
#define NEG_SLOPE 0.01f

// ---------------- K1: z = h @ W^T, s_src = z.a_l, s_dst = z.a_r ----------------
// tile: 128 rows x 64 cols, K-chunks of 64. 256 threads, each 4 rows x 8 cols.
#define BM 128
#define BK 64
#define LDH 68   // padded LDS stride (float4-aligned, conflict-free)

__global__ __launch_bounds__(256) void k1_gemm(
        const float* __restrict__ h, const float* __restrict__ W,
        const float* __restrict__ a_attn, float* __restrict__ z,
        float* __restrict__ s_src, float* __restrict__ s_dst) {
    __shared__ float h_lds[BM * LDH];
    __shared__ float w_lds[OUT_DIM * LDH];
    const int t  = threadIdx.x;
    const int tx = t & 7;    // col group (0..7)
    const int ty = t >> 3;   // row group (0..31)
    const int rb = blockIdx.x * BM;

    float acc[4][8];
#pragma unroll
    for (int i = 0; i < 4; ++i)
#pragma unroll
        for (int j = 0; j < 8; ++j) acc[i][j] = 0.f;

    for (int kc = 0; kc < IN_DIM; kc += BK) {
        __syncthreads();
#pragma unroll
        for (int l = 0; l < 8; ++l) {
            int f = t + 256 * l;
            int r = f >> 4;
            int k4 = f & 15;
            float4 v = make_float4(0.f, 0.f, 0.f, 0.f);
            if (rb + r < N_NODES)
                v = *(const float4*)(h + (size_t)(rb + r) * IN_DIM + kc + k4 * 4);
            *(float4*)(&h_lds[r * LDH + k4 * 4]) = v;
        }
#pragma unroll
        for (int l = 0; l < 4; ++l) {
            int f = t + 256 * l;
            int r = f >> 4;
            int k4 = f & 15;
            float4 v = *(const float4*)(W + (size_t)r * IN_DIM + kc + k4 * 4);
            *(float4*)(&w_lds[r * LDH + k4 * 4]) = v;
        }
        __syncthreads();
#pragma unroll 4
        for (int k = 0; k < BK; k += 4) {
            float4 hv[4], wv[8];
#pragma unroll
            for (int i = 0; i < 4; ++i)
                hv[i] = *(const float4*)(&h_lds[(ty + 32 * i) * LDH + k]);
#pragma unroll
            for (int j = 0; j < 8; ++j)
                wv[j] = *(const float4*)(&w_lds[(tx + 8 * j) * LDH + k]);
#pragma unroll
            for (int i = 0; i < 4; ++i)
#pragma unroll
                for (int j = 0; j < 8; ++j) {
                    acc[i][j] = fmaf(hv[i].x, wv[j].x, acc[i][j]);
                    acc[i][j] = fmaf(hv[i].y, wv[j].y, acc[i][j]);
                    acc[i][j] = fmaf(hv[i].z, wv[j].z, acc[i][j]);
                    acc[i][j] = fmaf(hv[i].w, wv[j].w, acc[i][j]);
                }
        }
    }

    float al[8], ar[8];
#pragma unroll
    for (int j = 0; j < 8; ++j) {
        al[j] = a_attn[tx + 8 * j];
        ar[j] = a_attn[OUT_DIM + tx + 8 * j];
    }

#pragma unroll
    for (int i = 0; i < 4; ++i) {
        int row = rb + ty + 32 * i;
        bool ok = row < N_NODES;
        float ps = 0.f, pd = 0.f;
#pragma unroll
        for (int j = 0; j < 8; ++j) {
            if (ok) z[(size_t)row * OUT_DIM + tx + 8 * j] = acc[i][j];
            ps = fmaf(acc[i][j], al[j], ps);
            pd = fmaf(acc[i][j], ar[j], pd);
        }
#pragma unroll
        for (int m = 1; m < 8; m <<= 1) {
            ps += __shfl_xor(ps, m, 64);
            pd += __shfl_xor(pd, m, 64);
        }
        if (ok && tx == 0) { s_src[row] = ps; s_dst[row] = pd; }
    }
}

// ---------------- CSR build ----------------
__global__ __launch_bounds__(256) void k_hist(const int* __restrict__ dst,
                                              int* __restrict__ cnt) {
    int i = blockIdx.x * 256 + threadIdx.x;
    if (i < N_EDGES) atomicAdd(&cnt[dst[i]], 1);
}

#define SCAN_I 8
#define SCAN_TILE 2048
#define SCAN_NB ((N_NODES + SCAN_TILE - 1) / SCAN_TILE)   // 49

__global__ __launch_bounds__(256) void k_scan1(const int* __restrict__ cnt,
                                               int* __restrict__ rowptr,
                                               int* __restrict__ blksums) {
    __shared__ int wsum[4];
    int t = threadIdx.x;
    int base = blockIdx.x * SCAN_TILE + t * SCAN_I;
    int v[SCAN_I];
    int s = 0;
#pragma unroll
    for (int i = 0; i < SCAN_I; ++i) {
        int idx = base + i;
        v[i] = (idx < N_NODES) ? cnt[idx] : 0;
        s += v[i];
    }
    int lane = t & 63, wv = t >> 6;
    int incl = s;
#pragma unroll
    for (int off = 1; off < 64; off <<= 1) {
        int n = __shfl_up(incl, off, 64);
        if (lane >= off) incl += n;
    }
    if (lane == 63) wsum[wv] = incl;
    __syncthreads();
    int woff = 0;
    for (int w = 0; w < wv; ++w) woff += wsum[w];
    int run = woff + incl - s;   // exclusive prefix for this thread
#pragma unroll
    for (int i = 0; i < SCAN_I; ++i) {
        int idx = base + i;
        if (idx < N_NODES) rowptr[idx] = run;
        run += v[i];
    }
    if (t == 255) blksums[blockIdx.x] = woff + incl;  // block total
}

__global__ void k_scan2(int* __restrict__ blksums) {
    int lane = threadIdx.x;
    int v = (lane < SCAN_NB) ? blksums[lane] : 0;
    int incl = v;
#pragma unroll
    for (int off = 1; off < 64; off <<= 1) {
        int n = __shfl_up(incl, off, 64);
        if (lane >= off) incl += n;
    }
    if (lane < SCAN_NB) blksums[lane] = incl - v;     // exclusive
}

__global__ __launch_bounds__(256) void k_scan3(int* __restrict__ rowptr,
                                               const int* __restrict__ blksums) {
    int i = blockIdx.x * 256 + threadIdx.x;
    if (i < N_NODES) rowptr[i] += blksums[i >> 11];
    if (i == 0) rowptr[N_NODES] = N_EDGES;
}

__global__ __launch_bounds__(256) void k_scatter(const int* __restrict__ src,
                                                 const int* __restrict__ dst,
                                                 const int* __restrict__ rowptr,
                                                 int* __restrict__ cursor,
                                                 int* __restrict__ col) {
    int i = blockIdx.x * 256 + threadIdx.x;
    if (i >= N_EDGES) return;
    int d = dst[i];
    int pos = rowptr[d] + atomicAdd(&cursor[d], 1);
    col[pos] = src[i];
}

// ---------------- gather: one wave per node, no atomics ----------------
__global__ __launch_bounds__(256) void k_gather(
        const int* __restrict__ rowptr, const int* __restrict__ col,
        const float* __restrict__ s_src, const float* __restrict__ s_dst,
        const float* __restrict__ z, float* __restrict__ out) {
    int lane = threadIdx.x & 63;
    int d = blockIdx.x * 4 + (threadIdx.x >> 6);   // grid covers exactly N_NODES
    int beg = rowptr[d], end = rowptr[d + 1];
    float sdd = s_dst[d];

    // phase A: segment max (lanes stride edges)
    float m = -INFINITY;
    for (int e = beg + lane; e < end; e += 64) {
        int s = col[e];
        float sc = s_src[s] + sdd;
        sc = sc > 0.f ? sc : sc * NEG_SLOPE;
        m = fmaxf(m, sc);
    }
#pragma unroll
    for (int off = 1; off < 64; off <<= 1)
        m = fmaxf(m, __shfl_xor(m, off, 64));

    // phase B: ex per lane-owned edge, broadcast via shfl, accumulate z rows
    float acc = 0.f, dsum = 0.f;
    for (int cbeg = beg; cbeg < end; cbeg += 64) {
        int cn = end - cbeg; if (cn > 64) cn = 64;
        int sl = 0; float exl = 0.f;
        if (lane < cn) {
            sl = col[cbeg + lane];
            float sc = s_src[sl] + sdd;
            sc = sc > 0.f ? sc : sc * NEG_SLOPE;
            exl = __expf(sc - m);
        }
        dsum += exl;
#pragma unroll 4
        for (int j = 0; j < cn; ++j) {
            int s  = __shfl(sl, j, 64);
            float ex = __shfl(exl, j, 64);
            acc = fmaf(ex, z[(size_t)s * OUT_DIM + lane], acc);
        }
    }
#pragma unroll
    for (int off = 1; off < 64; off <<= 1)
        dsum += __shfl_xor(dsum, off, 64);

    out[(size_t)d * OUT_DIM + lane] = (end > beg) ? acc / dsum : 0.f;
}

extern "C" void kernel_launch(void* const* d_in, const int* in_sizes, int n_in,
                              void* d_out, int out_size, void* d_ws, size_t ws_size,
                              hipStream_t stream) {
    const float* h      = (const float*)d_in[0];
    const float* W      = (const float*)d_in[1];
    const float* a_attn = (const float*)d_in[2];
    const int*   ei     = (const int*)d_in[3];
    const int* src = ei;
    const int* dst = ei + N_EDGES;
    float* out = (float*)d_out;

    auto rup = [](size_t x) { return (x + 511) & ~size_t(511); };
    char* ws = (char*)d_ws;
    float* z      = (float*)ws;  ws += rup((size_t)N_NODES * OUT_DIM * 4);
    float* s_src  = (float*)ws;  ws += rup((size_t)N_NODES * 4);
    float* s_dst  = (float*)ws;  ws += rup((size_t)N_NODES * 4);
    int*   rowptr = (int*)ws;    ws += rup(((size_t)N_NODES + 1) * 4);
    int*   cursor = (int*)ws;    ws += rup((size_t)N_NODES * 4);
    int*   col    = (int*)ws;    ws += rup((size_t)N_EDGES * 4);
    int*   blksums= (int*)ws;    ws += rup((size_t)SCAN_NB * 4);

    hipMemsetAsync(cursor, 0, (size_t)N_NODES * 4, stream);

    k1_gemm <<<(N_NODES + BM - 1) / BM, 256, 0, stream>>>(h, W, a_attn, z, s_src, s_dst);
    k_hist  <<<(N_EDGES + 255) / 256, 256, 0, stream>>>(dst, cursor);
    k_scan1 <<<SCAN_NB, 256, 0, stream>>>(cursor, rowptr, blksums);
    k_scan2 <<<1, 64, 0, stream>>>(blksums);
    k_scan3 <<<(N_NODES + 255) / 256, 256, 0, stream>>>(rowptr, blksums);
    hipMemsetAsync(cursor, 0, (size_t)N_NODES * 4, stream);
    k_scatter<<<(N_EDGES + 255) / 256, 256, 0, stream>>>(src, dst, rowptr, cursor, col);
    k_gather<<<N_NODES / 4, 256, 0, stream>>>(rowptr, col, s_src, s_dst, z, out);
}

// Round 3
// 406.387 us; speedup vs baseline: 1.8907x; 1.2030x over previous
//
#include <hip/hip_runtime.h>

#define N_NODES 100000
#define N_EDGES 1600000
#define IN_DIM  256
#define OUT_DIM 64
#define NEG_SLOPE 0.01f

typedef __attribute__((ext_vector_type(8))) short bf16x8;
typedef __attribute__((ext_vector_type(4))) float f32x4;

__device__ __forceinline__ short f2bf(float f) {           // RNE fp32->bf16
    unsigned u = __float_as_uint(f);
    return (short)((u + 0x7fffu + ((u >> 16) & 1u)) >> 16);
}
__device__ __forceinline__ float bflo(unsigned p) { return __uint_as_float(p << 16); }
__device__ __forceinline__ float bfhi(unsigned p) { return __uint_as_float(p & 0xffff0000u); }

// ---------------- K1: z = h @ W^T (bf16 MFMA), s_src = z.a_l, s_dst = z.a_r ----------------
// 256 thr = 4 waves; wave owns 32 rows x 64 cols; frags loaded straight from global.
__global__ __launch_bounds__(256) void k1_gemm(
        const float* __restrict__ h, const float* __restrict__ W,
        const float* __restrict__ a_attn, ushort* __restrict__ zb,
        float* __restrict__ s_src, float* __restrict__ s_dst) {
    const int lane = threadIdx.x & 63;
    const int w    = threadIdx.x >> 6;
    const int g    = lane >> 4;     // k-subgroup 0..3
    const int r16  = lane & 15;     // row (A) / col (B,D) within frag
    const int rb   = blockIdx.x * 128 + w * 32;

    f32x4 acc[2][4];
#pragma unroll
    for (int mr = 0; mr < 2; ++mr)
#pragma unroll
        for (int nr = 0; nr < 4; ++nr) acc[mr][nr] = (f32x4){0.f, 0.f, 0.f, 0.f};

    int rowa[2];
#pragma unroll
    for (int mr = 0; mr < 2; ++mr) {
        int r = rb + mr * 16 + r16;
        rowa[mr] = r < N_NODES ? r : N_NODES - 1;   // clamp; stores are guarded
    }

#pragma unroll 2
    for (int ks = 0; ks < 8; ++ks) {
        const int k0 = ks * 32 + g * 8;
        bf16x8 af[2], bfr[4];
#pragma unroll
        for (int mr = 0; mr < 2; ++mr) {
            const float* p = h + (size_t)rowa[mr] * IN_DIM + k0;
            float4 lo = *(const float4*)p;
            float4 hi = *(const float4*)(p + 4);
            bf16x8 v;
            v[0] = f2bf(lo.x); v[1] = f2bf(lo.y); v[2] = f2bf(lo.z); v[3] = f2bf(lo.w);
            v[4] = f2bf(hi.x); v[5] = f2bf(hi.y); v[6] = f2bf(hi.z); v[7] = f2bf(hi.w);
            af[mr] = v;
        }
#pragma unroll
        for (int nr = 0; nr < 4; ++nr) {
            const float* p = W + (size_t)(nr * 16 + r16) * IN_DIM + k0;
            float4 lo = *(const float4*)p;
            float4 hi = *(const float4*)(p + 4);
            bf16x8 v;
            v[0] = f2bf(lo.x); v[1] = f2bf(lo.y); v[2] = f2bf(lo.z); v[3] = f2bf(lo.w);
            v[4] = f2bf(hi.x); v[5] = f2bf(hi.y); v[6] = f2bf(hi.z); v[7] = f2bf(hi.w);
            bfr[nr] = v;
        }
#pragma unroll
        for (int mr = 0; mr < 2; ++mr)
#pragma unroll
            for (int nr = 0; nr < 4; ++nr)
                acc[mr][nr] = __builtin_amdgcn_mfma_f32_16x16x32_bf16(
                                  af[mr], bfr[nr], acc[mr][nr], 0, 0, 0);
    }

    // D layout: col = lane&15, row = (lane>>4)*4 + reg   [HW-verified]
    float al[4], ar[4];
#pragma unroll
    for (int nr = 0; nr < 4; ++nr) {
        al[nr] = a_attn[nr * 16 + r16];
        ar[nr] = a_attn[OUT_DIM + nr * 16 + r16];
    }
#pragma unroll
    for (int mr = 0; mr < 2; ++mr) {
#pragma unroll
        for (int rr = 0; rr < 4; ++rr) {
            float ps = 0.f, pd = 0.f;
#pragma unroll
            for (int nr = 0; nr < 4; ++nr) {
                ps = fmaf(acc[mr][nr][rr], al[nr], ps);
                pd = fmaf(acc[mr][nr][rr], ar[nr], pd);
            }
#pragma unroll
            for (int m = 1; m < 16; m <<= 1) {
                ps += __shfl_xor(ps, m, 64);
                pd += __shfl_xor(pd, m, 64);
            }
            int row = rb + mr * 16 + g * 4 + rr;
            if (r16 == 0 && row < N_NODES) { s_src[row] = ps; s_dst[row] = pd; }
        }
#pragma unroll
        for (int nr = 0; nr < 4; ++nr)
#pragma unroll
            for (int rr = 0; rr < 4; ++rr) {
                int row = rb + mr * 16 + g * 4 + rr;
                if (row < N_NODES)
                    zb[(size_t)row * OUT_DIM + nr * 16 + r16] = (ushort)f2bf(acc[mr][nr][rr]);
            }
    }
}

// ---------------- CSR build ----------------
__global__ __launch_bounds__(256) void k_hist(const int* __restrict__ dst,
                                              int* __restrict__ cnt) {
    int i = blockIdx.x * 256 + threadIdx.x;
    if (i < N_EDGES) atomicAdd(&cnt[dst[i]], 1);
}

#define SCAN_I 8
#define SCAN_TILE 2048
#define SCAN_NB ((N_NODES + SCAN_TILE - 1) / SCAN_TILE)   // 49

__global__ __launch_bounds__(256) void k_scan1(const int* __restrict__ cnt,
                                               int* __restrict__ rowptr,
                                               int* __restrict__ blksums) {
    __shared__ int wsum[4];
    int t = threadIdx.x;
    int base = blockIdx.x * SCAN_TILE + t * SCAN_I;
    int v[SCAN_I];
    int s = 0;
#pragma unroll
    for (int i = 0; i < SCAN_I; ++i) {
        int idx = base + i;
        v[i] = (idx < N_NODES) ? cnt[idx] : 0;
        s += v[i];
    }
    int lane = t & 63, wv = t >> 6;
    int incl = s;
#pragma unroll
    for (int off = 1; off < 64; off <<= 1) {
        int n = __shfl_up(incl, off, 64);
        if (lane >= off) incl += n;
    }
    if (lane == 63) wsum[wv] = incl;
    __syncthreads();
    int woff = 0;
    for (int w = 0; w < wv; ++w) woff += wsum[w];
    int run = woff + incl - s;
#pragma unroll
    for (int i = 0; i < SCAN_I; ++i) {
        int idx = base + i;
        if (idx < N_NODES) rowptr[idx] = run;
        run += v[i];
    }
    if (t == 255) blksums[blockIdx.x] = woff + incl;
}

__global__ void k_scan2(int* __restrict__ blksums) {
    int lane = threadIdx.x;
    int v = (lane < SCAN_NB) ? blksums[lane] : 0;
    int incl = v;
#pragma unroll
    for (int off = 1; off < 64; off <<= 1) {
        int n = __shfl_up(incl, off, 64);
        if (lane >= off) incl += n;
    }
    if (lane < SCAN_NB) blksums[lane] = incl - v;
}

__global__ __launch_bounds__(256) void k_scan3(int* __restrict__ rowptr,
                                               const int* __restrict__ blksums) {
    int i = blockIdx.x * 256 + threadIdx.x;
    if (i < N_NODES) rowptr[i] += blksums[i >> 11];
    if (i == 0) rowptr[N_NODES] = N_EDGES;
}

__global__ __launch_bounds__(256) void k_scatter(const int* __restrict__ src,
                                                 const int* __restrict__ dst,
                                                 const int* __restrict__ rowptr,
                                                 int* __restrict__ cursor,
                                                 int* __restrict__ col) {
    int i = blockIdx.x * 256 + threadIdx.x;
    if (i >= N_EDGES) return;
    int d = dst[i];
    int pos = rowptr[d] + atomicAdd(&cursor[d], 1);
    col[pos] = src[i];
}

// ---------------- gather: wave/node, 4 edges concurrent, bf16 z ----------------
__global__ __launch_bounds__(256) void k_gather(
        const int* __restrict__ rowptr, const int* __restrict__ col,
        const float* __restrict__ s_src, const float* __restrict__ s_dst,
        const ushort* __restrict__ zb, float* __restrict__ out) {
    const int lane = threadIdx.x & 63;
    const int d = blockIdx.x * 4 + (threadIdx.x >> 6);
    const int jg = lane >> 4;      // edge sub-slot 0..3
    const int q  = lane & 15;      // dim quad
    const int beg = rowptr[d], end = rowptr[d + 1];
    const int deg = end - beg;
    const float sdd = s_dst[d];

    float4 acc = make_float4(0.f, 0.f, 0.f, 0.f);
    float dsum = 0.f;

    if (deg <= 64) {
        int sl = 0; float sc = -INFINITY;
        if (lane < deg) {
            sl = col[beg + lane];
            float t = s_src[sl] + sdd;
            sc = t > 0.f ? t : t * NEG_SLOPE;
        }
        float m = sc;
#pragma unroll
        for (int off = 1; off < 64; off <<= 1) m = fmaxf(m, __shfl_xor(m, off, 64));
        float exl = (lane < deg) ? __expf(sc - m) : 0.f;
        dsum = exl;
#pragma unroll 2
        for (int j0 = 0; j0 < deg; j0 += 4) {
            int e = j0 + jg;
            int ei = e < 63 ? e : 63;
            int   s  = __shfl(sl,  ei, 64);
            float ex = __shfl(exl, ei, 64);
            if (e < deg) {
                uint2 v = *(const uint2*)(zb + (size_t)s * OUT_DIM + q * 4);
                acc.x = fmaf(ex, bflo(v.x), acc.x);
                acc.y = fmaf(ex, bfhi(v.x), acc.y);
                acc.z = fmaf(ex, bflo(v.y), acc.z);
                acc.w = fmaf(ex, bfhi(v.y), acc.w);
            }
        }
    } else {
        float m = -INFINITY;
        for (int e = beg + lane; e < end; e += 64) {
            int s = col[e];
            float t = s_src[s] + sdd;
            t = t > 0.f ? t : t * NEG_SLOPE;
            m = fmaxf(m, t);
        }
#pragma unroll
        for (int off = 1; off < 64; off <<= 1) m = fmaxf(m, __shfl_xor(m, off, 64));
        for (int cbeg = beg; cbeg < end; cbeg += 64) {
            int cn = end - cbeg; if (cn > 64) cn = 64;
            int sl = 0; float exl = 0.f;
            if (lane < cn) {
                sl = col[cbeg + lane];
                float t = s_src[sl] + sdd;
                t = t > 0.f ? t : t * NEG_SLOPE;
                exl = __expf(t - m);
            }
            dsum += exl;
            for (int j0 = 0; j0 < cn; j0 += 4) {
                int e = j0 + jg;
                int ei = e < 63 ? e : 63;
                int   s  = __shfl(sl,  ei, 64);
                float ex = __shfl(exl, ei, 64);
                if (e < cn) {
                    uint2 v = *(const uint2*)(zb + (size_t)s * OUT_DIM + q * 4);
                    acc.x = fmaf(ex, bflo(v.x), acc.x);
                    acc.y = fmaf(ex, bfhi(v.x), acc.y);
                    acc.z = fmaf(ex, bflo(v.y), acc.z);
                    acc.w = fmaf(ex, bfhi(v.y), acc.w);
                }
            }
        }
    }

    // fold the 4 edge-slots (lanes ^16, ^32)
    acc.x += __shfl_xor(acc.x, 16, 64); acc.x += __shfl_xor(acc.x, 32, 64);
    acc.y += __shfl_xor(acc.y, 16, 64); acc.y += __shfl_xor(acc.y, 32, 64);
    acc.z += __shfl_xor(acc.z, 16, 64); acc.z += __shfl_xor(acc.z, 32, 64);
    acc.w += __shfl_xor(acc.w, 16, 64); acc.w += __shfl_xor(acc.w, 32, 64);
#pragma unroll
    for (int off = 1; off < 64; off <<= 1) dsum += __shfl_xor(dsum, off, 64);

    if (jg == 0) {
        float inv = (deg > 0) ? 1.f / dsum : 0.f;
        float4 o;
        o.x = acc.x * inv; o.y = acc.y * inv; o.z = acc.z * inv; o.w = acc.w * inv;
        *(float4*)(out + (size_t)d * OUT_DIM + q * 4) = o;
    }
}

extern "C" void kernel_launch(void* const* d_in, const int* in_sizes, int n_in,
                              void* d_out, int out_size, void* d_ws, size_t ws_size,
                              hipStream_t stream) {
    const float* h      = (const float*)d_in[0];
    const float* W      = (const float*)d_in[1];
    const float* a_attn = (const float*)d_in[2];
    const int*   ei     = (const int*)d_in[3];
    const int* src = ei;
    const int* dst = ei + N_EDGES;
    float* out = (float*)d_out;

    auto rup = [](size_t x) { return (x + 511) & ~size_t(511); };
    char* ws = (char*)d_ws;
    ushort* zb    = (ushort*)ws; ws += rup((size_t)N_NODES * OUT_DIM * 2);
    float* s_src  = (float*)ws;  ws += rup((size_t)N_NODES * 4);
    float* s_dst  = (float*)ws;  ws += rup((size_t)N_NODES * 4);
    int*   rowptr = (int*)ws;    ws += rup(((size_t)N_NODES + 1) * 4);
    int*   cursor = (int*)ws;    ws += rup((size_t)N_NODES * 4);
    int*   col    = (int*)ws;    ws += rup((size_t)N_EDGES * 4);
    int*   blksums= (int*)ws;    ws += rup((size_t)SCAN_NB * 4);

    hipMemsetAsync(cursor, 0, (size_t)N_NODES * 4, stream);

    k1_gemm <<<(N_NODES + 127) / 128, 256, 0, stream>>>(h, W, a_attn, zb, s_src, s_dst);
    k_hist  <<<(N_EDGES + 255) / 256, 256, 0, stream>>>(dst, cursor);
    k_scan1 <<<SCAN_NB, 256, 0, stream>>>(cursor, rowptr, blksums);
    k_scan2 <<<1, 64, 0, stream>>>(blksums);
    k_scan3 <<<(N_NODES + 255) / 256, 256, 0, stream>>>(rowptr, blksums);
    hipMemsetAsync(cursor, 0, (size_t)N_NODES * 4, stream);
    k_scatter<<<(N_EDGES + 255) / 256, 256, 0, stream>>>(src, dst, rowptr, cursor, col);
    k_gather<<<N_NODES / 4, 256, 0, stream>>>(rowptr, col, s_src, s_dst, zb, out);
}